// Round 12
// baseline (439.234 us; speedup 1.0000x reference)
//
#include <hip/hip_runtime.h>
#include <hip/hip_bf16.h>

typedef unsigned short u16;
typedef unsigned int u32;
typedef __attribute__((ext_vector_type(4))) float f32x4;
typedef __attribute__((ext_vector_type(16))) float f32x16;
typedef __attribute__((ext_vector_type(8))) __bf16 bf16x8;
typedef __attribute__((ext_vector_type(4))) u16 u16x4;
typedef __attribute__((ext_vector_type(8))) u16 u16x8;
typedef __attribute__((ext_vector_type(4))) u32 u32x4;

#define START_POS 3072
#define NKV 4096
#define HD_ 128
#define SEQ 1024
#define DIN_ 4096
#define DQKV 6144

__device__ __forceinline__ void gll16(const void* g, void* l) {
  __builtin_amdgcn_global_load_lds((const __attribute__((address_space(1))) u32*)g,
                                   (__attribute__((address_space(3))) u32*)l, 16, 0, 0);
}
__device__ __forceinline__ u16 f2bf(float f) {
  u32 u = __builtin_bit_cast(u32, f);
  return (u16)((u + 0x7fffu + ((u >> 16) & 1u)) >> 16);
}
__device__ __forceinline__ u32 pack2bf(float a, float b) {
  __hip_bfloat162 t = __float22bfloat162_rn(float2{a, b});  // low=a, high=b, RNE
  u32 u; __builtin_memcpy(&u, &t, 4);
  return u;
}
__device__ __forceinline__ f32x4 mfma16(bf16x8 a, bf16x8 b, f32x4 c) {
  return __builtin_amdgcn_mfma_f32_16x16x32_bf16(a, b, c, 0, 0, 0);
}
__device__ __forceinline__ f32x16 mfma32(bf16x8 a, bf16x8 b, f32x16 c) {
  return __builtin_amdgcn_mfma_f32_32x32x16_bf16(a, b, c, 0, 0, 0);
}

// ---- transpose+convert W f32 [K=4096][N] -> Wt bf16 [N][4096] ----
__global__ __launch_bounds__(256) void wtrans(const float* __restrict__ W,
    u16* __restrict__ Wt, int N, int ntn, int row_off)
{
  __shared__ float T[64][68];
  int bid = blockIdx.x;
  int nt = bid % ntn, kt = bid / ntn;
  int t = threadIdx.x;
  int kl = t >> 4, nl4 = (t & 15) << 2;
#pragma unroll
  for (int r = 0; r < 4; r++) {
    int row = r * 16 + kl;
    f32x4 v = *(const f32x4*)(W + (size_t)(kt * 64 + row) * N + nt * 64 + nl4);
    T[row][nl4] = v[0]; T[row][nl4 + 1] = v[1]; T[row][nl4 + 2] = v[2]; T[row][nl4 + 3] = v[3];
  }
  __syncthreads();
  int nl = t >> 2, k0 = (t & 3) << 4;
  u16x8 lo, hi;
#pragma unroll
  for (int j = 0; j < 8; j++) lo[j] = f2bf(T[k0 + j][nl]);
#pragma unroll
  for (int j = 0; j < 8; j++) hi[j] = f2bf(T[k0 + 8 + j][nl]);
  u16* dst = Wt + (size_t)(row_off + nt * 64 + nl) * 4096 + kt * 64 + k0;
  *(u16x8*)dst = lo;
  *(u16x8*)(dst + 8) = hi;
}

// ---- f32 -> bf16 convert ----
__global__ __launch_bounds__(256) void cvt_bf16(const float* __restrict__ src,
    u16* __restrict__ dst, int n4)
{
  int i = blockIdx.x * 256 + threadIdx.x;
  if (i >= n4) return;
  f32x4 v = *(const f32x4*)(src + (size_t)i * 4);
  u16x4 o;
#pragma unroll
  for (int j = 0; j < 4; j++) o[j] = f2bf(v[j]);
  *(u16x4*)(dst + (size_t)i * 4) = o;
}

// ---- bf16 GEMM: C[M][N] f32 = A[M][K] * Bt[N][K], 128x64 tile, BK=32 ----
__global__ __launch_bounds__(256) void gemm_bt(
    const u16* __restrict__ A, const u16* __restrict__ Bt,
    float* __restrict__ C, int N, int K, int nbx)
{
  __shared__ u16 As[128 * 32];
  __shared__ u16 Bs[64 * 32];
  int nwg = (int)gridDim.x;
  int orig = blockIdx.x;
  int q8 = nwg >> 3, r8 = nwg & 7;
  int xcd = orig & 7, jj = orig >> 3;
  int wgid = (xcd < r8 ? xcd * (q8 + 1) : r8 * (q8 + 1) + (xcd - r8) * q8) + jj;
  int by = wgid / nbx, bx = wgid % nbx;
  int tid = threadIdx.x, lane = tid & 63, wid = tid >> 6;
  int wr = wid >> 1, wc = wid & 1;
  int c = lane & 15, hh = lane >> 4;
  int lrow = wid * 16 + (lane >> 2);       // 0..63
  int ksl = (lane & 3) << 3;
  const u16* aS0 = A + (size_t)(by * 128 + lrow) * K + ksl;
  const u16* bS0 = Bt + (size_t)(bx * 64 + lrow) * K + ksl;
  u16* aL0 = As + wid * 512;
  u16* bL0 = Bs + wid * 512;
  f32x4 acc[4][2] = {};
  for (int k0 = 0; k0 < K; k0 += 32) {
    gll16(aS0 + k0, aL0);
    gll16(aS0 + (size_t)64 * K + k0, aL0 + 2048);
    gll16(bS0 + k0, bL0);
    __syncthreads();
    bf16x8 af[4], bf[2];
#pragma unroll
    for (int i = 0; i < 4; i++)
      af[i] = *(const bf16x8*)(As + (wr * 64 + i * 16 + c) * 32 + hh * 8);
#pragma unroll
    for (int i = 0; i < 2; i++)
      bf[i] = *(const bf16x8*)(Bs + (wc * 32 + i * 16 + c) * 32 + hh * 8);
#pragma unroll
    for (int mi = 0; mi < 4; mi++)
#pragma unroll
      for (int ni = 0; ni < 2; ni++)
        acc[mi][ni] = mfma16(af[mi], bf[ni], acc[mi][ni]);
    __syncthreads();
  }
  int row0 = by * 128 + wr * 64 + hh * 4;
  int col0 = bx * 64 + wc * 32 + c;
#pragma unroll
  for (int mi = 0; mi < 4; mi++)
#pragma unroll
    for (int ni = 0; ni < 2; ni++)
#pragma unroll
      for (int i = 0; i < 4; i++)
        C[(size_t)(row0 + mi * 16 + i) * N + col0 + ni * 16] = acc[mi][ni][i];
}

// ---- RoPE on q part of qkv -> qb bf16 [32][1024][128] ----
__global__ __launch_bounds__(256) void rope_q(const float* __restrict__ qkv,
    const float* __restrict__ cosb, const float* __restrict__ sinb, u16* __restrict__ qb)
{
  int tid = blockIdx.x * 256 + threadIdx.x;  // 524288
  int dq = tid & 15, h = (tid >> 4) & 31, s = tid >> 9;
  int d = dq << 2;
  const float* base = qkv + (size_t)s * DQKV + h * HD_ + d;
  f32x4 a = *(const f32x4*)base;
  f32x4 b2 = *(const f32x4*)(base + 64);
  f32x4 cc = *(const f32x4*)(cosb + (size_t)(START_POS + s) * HD_ + d);
  f32x4 sn = *(const f32x4*)(sinb + (size_t)(START_POS + s) * HD_ + d);
  u16x4 o1, o2;
#pragma unroll
  for (int i = 0; i < 4; i++) {
    o1[i] = f2bf(a[i] * cc[i] - b2[i] * sn[i]);
    o2[i] = f2bf(b2[i] * cc[i] + a[i] * sn[i]);
  }
  u16* dst = qb + ((size_t)h * SEQ + s) * HD_ + d;
  *(u16x4*)dst = o1;
  *(u16x4*)(dst + 64) = o2;
}

// ---- RoPE on k part -> keys f32 output (pos>=3072) + kb bf16 ----
__global__ __launch_bounds__(256) void rope_k(const float* __restrict__ qkv,
    const float* __restrict__ cosb, const float* __restrict__ sinb,
    float* __restrict__ keys, u16* __restrict__ kbb)
{
  int tid = blockIdx.x * 256 + threadIdx.x;  // 131072
  int dq = tid & 15, g = (tid >> 4) & 7, s = tid >> 7;
  int d = dq << 2;
  const float* base = qkv + (size_t)s * DQKV + DIN_ + g * HD_ + d;
  f32x4 a = *(const f32x4*)base;
  f32x4 b2 = *(const f32x4*)(base + 64);
  f32x4 cc = *(const f32x4*)(cosb + (size_t)(START_POS + s) * HD_ + d);
  f32x4 sn = *(const f32x4*)(sinb + (size_t)(START_POS + s) * HD_ + d);
  f32x4 o1, o2;
  u16x4 p1, p2;
#pragma unroll
  for (int i = 0; i < 4; i++) {
    o1[i] = a[i] * cc[i] - b2[i] * sn[i];
    o2[i] = b2[i] * cc[i] + a[i] * sn[i];
    p1[i] = f2bf(o1[i]);
    p2[i] = f2bf(o2[i]);
  }
  size_t off = ((size_t)g * NKV + START_POS + s) * HD_ + d;
  *(f32x4*)(keys + off) = o1;
  *(f32x4*)(keys + off + 64) = o2;
  *(u16x4*)(kbb + off) = p1;
  *(u16x4*)(kbb + off + 64) = p2;
}

// ---- copy v part -> values f32 output (pos>=3072) ----
__global__ __launch_bounds__(256) void copy_vnew(const float* __restrict__ qkv,
    float* __restrict__ values)
{
  int tid = blockIdx.x * 256 + threadIdx.x;  // 262144
  int dq = tid & 31, g = (tid >> 5) & 7, s = tid >> 8;
  int d = dq << 2;
  f32x4 v = *(const f32x4*)(qkv + (size_t)s * DQKV + DIN_ + 1024 + g * HD_ + d);
  *(f32x4*)(values + ((size_t)g * NKV + START_POS + s) * HD_ + d) = v;
}

// ---- copy prev_k/prev_v -> keys/values f32 outputs + kb bf16 ----
__global__ __launch_bounds__(256) void prev_copy(const float* __restrict__ pk,
    const float* __restrict__ pv, float* __restrict__ keys, float* __restrict__ values,
    u16* __restrict__ kbb)
{
  int idx = blockIdx.x * 256 + threadIdx.x;  // 786432 quads
  int d4 = idx & 31;
  int rest = idx >> 5;
  int p = rest % 3072, g = rest / 3072;
  f32x4 kq = *(const f32x4*)(pk + (size_t)idx * 4);
  f32x4 vq = *(const f32x4*)(pv + (size_t)idx * 4);
  size_t off = ((size_t)g * NKV + p) * HD_ + d4 * 4;
  *(f32x4*)(keys + off) = kq;
  *(f32x4*)(values + off) = vq;
  u16x4 kb4;
#pragma unroll
  for (int i = 0; i < 4; i++) kb4[i] = f2bf(kq[i]);
  *(u16x4*)(kbb + off) = kb4;
}

// ---- build vT bf16 [8][128][4096] from prev_v (pos<3072) / qkv v-cols ----
__global__ __launch_bounds__(256) void vtrans(const float* __restrict__ pv,
    const float* __restrict__ qkv, u16* __restrict__ vT)
{
  __shared__ float T[64][68];
  int bid = blockIdx.x;  // 1024 = g(8) * pt(64) * dt(2)
  int dt = bid & 1, pt = (bid >> 1) & 63, g = bid >> 7;
  int t = threadIdx.x;
  int pl = t >> 4, dl4 = (t & 15) << 2;
#pragma unroll
  for (int r = 0; r < 4; r++) {
    int row = r * 16 + pl;
    int pos = pt * 64 + row;
    f32x4 v;
    if (pos < START_POS)
      v = *(const f32x4*)(pv + ((size_t)g * START_POS + pos) * HD_ + dt * 64 + dl4);
    else
      v = *(const f32x4*)(qkv + (size_t)(pos - START_POS) * DQKV + 5120 + g * HD_ + dt * 64 + dl4);
    T[row][dl4] = v[0]; T[row][dl4 + 1] = v[1]; T[row][dl4 + 2] = v[2]; T[row][dl4 + 3] = v[3];
  }
  __syncthreads();
  int dl = t >> 2, p0 = (t & 3) << 4;
  u16x8 lo, hi;
#pragma unroll
  for (int j = 0; j < 8; j++) lo[j] = f2bf(T[p0 + j][dl]);
#pragma unroll
  for (int j = 0; j < 8; j++) hi[j] = f2bf(T[p0 + 8 + j][dl]);
  u16* dst = vT + ((size_t)g * HD_ + dt * 64 + dl) * NKV + pt * 64 + p0;
  *(u16x8*)dst = lo;
  *(u16x8*)(dst + 8) = hi;
}

// ---- flash attention v6: barrier-free 1-wave blocks, counted vmcnt (T4),
// ---- K dbuf in LDS (16KB), V direct-to-registers (T14 issue-early/use-late).
// ---- 2048 blocks x 64 thr = 8 independent waves/CU. Verified v5 compute core. ----
__global__ __launch_bounds__(64, 2) void attn_fwd(
    const u16* __restrict__ qb, const u16* __restrict__ kb,
    const u16* __restrict__ vT, float* __restrict__ Opart, float* __restrict__ Ml)
{
  __shared__ u16 Ks[2 * 32 * 128];   // dbuf K, 16B-slot XOR swizzle
  const float C2 = 0.12751744f;      // log2(e)/sqrt(128)
  int bid = blockIdx.x;
  int g = bid & 7, r_ = bid >> 3;    // XCD x owns KV group g=x; r_ in [0,256)
  int sp = r_ >> 7, rr = r_ & 127;
  int h = g * 4 + (rr >> 5), qc = rr & 31;
  int lane = threadIdx.x;            // 0..63, one wave
  int c32 = lane & 31, h8 = lane >> 5;
  int qw0 = qc * 32;
  bf16x8 Qf[8];
#pragma unroll
  for (int dc = 0; dc < 8; dc++)
    Qf[dc] = *(const bf16x8*)(qb + ((size_t)(h * 1024 + qw0 + c32)) * 128 + dc * 16 + h8 * 8);
  f32x16 O0 = {}, O1 = {}, O2 = {}, O3 = {};
  float Mx = -1e30f, Ls = 0.f;
  // tiles: ntt = 97+qc; balanced split at th
  int ntt = 97 + qc;
  int th = (98 + qc) >> 1;
  int t0 = sp ? th : 0;
  int t1 = sp ? ntt : th;

#define STAGE_K(tt, bo) do { \
  _Pragma("unroll") \
  for (int r = 0; r < 8; r++) { \
    int s = r * 64 + lane; \
    int krow = s >> 4, sl = s & 15; \
    gll16(kb + ((size_t)(g * 4096 + (tt) * 32 + krow)) * 128 + (sl ^ (krow & 7)) * 8, \
          Ks + (bo) + r * 512); \
  } \
} while (0)

  int cur = 0;
  STAGE_K(t0, 0);                    // 8 loads in flight
  for (int t = t0; t < t1; t++) {
    // prior ds_reads fully drained before overwriting the other buffer
    asm volatile("s_waitcnt lgkmcnt(0)" ::: "memory");
    // V(t) -> registers (issue early; consumed after QK^T+softmax)
    bf16x8 vr[4][2];
#pragma unroll
    for (int db = 0; db < 4; db++)
#pragma unroll
      for (int kc = 0; kc < 2; kc++)
        vr[db][kc] = *(const bf16x8*)(vT + ((size_t)(g * 128 + db * 32 + c32)) * 4096
                                      + t * 32 + kc * 16 + h8 * 8);
    if (t + 1 < t1) {
      STAGE_K(t + 1, (cur ^ 1) * 4096);
      asm volatile("s_waitcnt vmcnt(16)" ::: "memory");  // K(t) landed; K(t+1)+V(t) in flight
    } else {
      asm volatile("s_waitcnt vmcnt(8)" ::: "memory");   // K(t) landed; V(t) in flight
    }
    __builtin_amdgcn_sched_barrier(0);
    const u16* Kb = Ks + cur * 4096;
    // S^T = K Q^T : kv rows 0..31 of this tile; col = c32 = q
    f32x16 S0 = {};
#pragma unroll
    for (int dc = 0; dc < 8; dc++) {
      int sx = (2 * dc + h8) ^ (c32 & 7);
      bf16x8 k0 = *(const bf16x8*)(Kb + (size_t)c32 * 128 + sx * 8);
      S0 = mfma32(k0, Qf[dc], S0);
    }
    // causal mask (only near-diagonal tiles of sp=1)
    if (t * 32 + 31 > START_POS + qw0) {
      int qa = START_POS + qw0 + c32;
#pragma unroll
      for (int r = 0; r < 16; r++) {
        int kvo = t * 32 + (r & 3) + 8 * (r >> 2) + 4 * h8;
        if (kvo > qa) S0[r] = -1e30f;
      }
    }
    // row max: 15-op tree + cross-half via shfl_xor(32)
    float tm[16];
#pragma unroll
    for (int r = 0; r < 16; r++) tm[r] = S0[r];
#pragma unroll
    for (int sft = 8; sft >= 1; sft >>= 1)
#pragma unroll
      for (int r = 0; r < sft; r++) tm[r] = fmaxf(tm[r], tm[r + sft]);
    float full = fmaxf(tm[0], __shfl_xor(tm[0], 32));
    // defer-max (T13)
    if (!__all(full <= Mx + 62.0f)) {
      float Mn = fmaxf(Mx, full);
      float al = exp2f((Mx - Mn) * C2);
      Mx = Mn;
      Ls *= al;
#pragma unroll
      for (int r = 0; r < 16; r++) { O0[r] *= al; O1[r] *= al; O2[r] *= al; O3[r] *= al; }
    }
#pragma unroll
    for (int r = 0; r < 16; r++) S0[r] = exp2f((S0[r] - Mx) * C2);
    // row sum
    float ts[16];
#pragma unroll
    for (int r = 0; r < 16; r++) ts[r] = S0[r];
#pragma unroll
    for (int sft = 8; sft >= 1; sft >>= 1)
#pragma unroll
      for (int r = 0; r < sft; r++) ts[r] = ts[r] + ts[r + sft];
    Ls += ts[0] + __shfl_xor(ts[0], 32);
    // pack P (v_cvt_pk_bf16_f32 via intrinsic) + cross-half exchange (verified routing)
    u32 pk0[8], x0[8];
#pragma unroll
    for (int m = 0; m < 8; m++) pk0[m] = pack2bf(S0[2 * m], S0[2 * m + 1]);
#pragma unroll
    for (int m = 0; m < 8; m++) x0[m] = __shfl_xor(pk0[m], 32);
    bf16x8 pbf[2];
    {
      u32x4 f0 = { h8 ? x0[2] : pk0[0], h8 ? x0[3] : pk0[1],
                   h8 ? pk0[2] : x0[0], h8 ? pk0[3] : x0[1] };
      u32x4 f1 = { h8 ? x0[6] : pk0[4], h8 ? x0[7] : pk0[5],
                   h8 ? pk0[6] : x0[4], h8 ? pk0[7] : x0[5] };
      pbf[0] = __builtin_bit_cast(bf16x8, f0);
      pbf[1] = __builtin_bit_cast(bf16x8, f1);
    }
    // O^T += V^T P^T  (V from registers; vr[db][kc] = V^T[32db+c32][kc*16+8h8 ..])
#pragma unroll
    for (int kc = 0; kc < 2; kc++) {
      O0 = mfma32(vr[0][kc], pbf[kc], O0);
      O1 = mfma32(vr[1][kc], pbf[kc], O1);
      O2 = mfma32(vr[2][kc], pbf[kc], O2);
      O3 = mfma32(vr[3][kc], pbf[kc], O3);
    }
    cur ^= 1;
  }
#undef STAGE_K
  // epilogue: raw partial O (f32) + (Mx, Ls)
  {
    float* Orow = Opart + (size_t)sp * 4194304 + (size_t)(qw0 + c32) * 4096 + h * 128;
#pragma unroll
    for (int a = 0; a < 4; a++) {
      f32x4 o0, o1, o2, o3;
#pragma unroll
      for (int b = 0; b < 4; b++) {
        o0[b] = O0[4 * a + b]; o1[b] = O1[4 * a + b];
        o2[b] = O2[4 * a + b]; o3[b] = O3[4 * a + b];
      }
      int d0 = 8 * a + 4 * h8;
      *(f32x4*)(Orow + d0) = o0;
      *(f32x4*)(Orow + 32 + d0) = o1;
      *(f32x4*)(Orow + 64 + d0) = o2;
      *(f32x4*)(Orow + 96 + d0) = o3;
    }
    if (h8 == 0) {
      float* mp = Ml + ((size_t)(sp * 32 + h) * 1024 + qw0 + c32) * 2;
      mp[0] = Mx; mp[1] = Ls;
    }
  }
}

// ---- combine the two KV-split halves -> ctxb bf16 ----
__global__ __launch_bounds__(256) void attn_combine(const float* __restrict__ Opart,
    const float* __restrict__ Ml, u16* __restrict__ ctxb)
{
  int idx = blockIdx.x * 256 + threadIdx.x;  // 1048576
  int q = idx >> 10, c4 = idx & 1023;
  int col = c4 * 4, h = col >> 7;
  const float* m0p = Ml + ((size_t)h * 1024 + q) * 2;
  const float* m1p = Ml + ((size_t)(32 + h) * 1024 + q) * 2;
  float m0 = m0p[0], l0 = m0p[1];
  float m1 = m1p[0], l1 = m1p[1];
  float M = fmaxf(m0, m1);
  float w0 = exp2f((m0 - M) * 0.12751744f);
  float w1 = exp2f((m1 - M) * 0.12751744f);
  float inv = 1.0f / (l0 * w0 + l1 * w1);
  f32x4 a = *(const f32x4*)(Opart + (size_t)q * 4096 + col);
  f32x4 b = *(const f32x4*)(Opart + 4194304 + (size_t)q * 4096 + col);
  u16x4 o;
#pragma unroll
  for (int i = 0; i < 4; i++) o[i] = f2bf((a[i] * w0 + b[i] * w1) * inv);
  *(u16x4*)(ctxb + (size_t)q * 4096 + col) = o;
}

extern "C" void kernel_launch(void* const* d_in, const int* in_sizes, int n_in,
                              void* d_out, int out_size, void* d_ws, size_t ws_size,
                              hipStream_t stream) {
  const float* x      = (const float*)d_in[0];
  const float* cosb   = (const float*)d_in[2];
  const float* sinb   = (const float*)d_in[3];
  const float* prev_k = (const float*)d_in[5];
  const float* prev_v = (const float*)d_in[6];
  const float* Wq     = (const float*)d_in[7];
  const float* Wk     = (const float*)d_in[8];
  const float* Wv     = (const float*)d_in[9];
  const float* Wo     = (const float*)d_in[10];

  // workspace layout (~144 MB)
  u16* Wt_proj = (u16*)d_ws;                                  // [6144][4096] bf16 (48MB)
  u16* Wt_out  = Wt_proj + (size_t)6144 * 4096;               // [4096][4096] bf16
  u16* xb      = Wt_out + (size_t)4096 * 4096;                // [1024][4096] bf16
  float* qkv   = (float*)(xb + (size_t)1024 * 4096);          // [1024][6144] f32
  u16* qb      = (u16*)(qkv + (size_t)1024 * 6144);           // [32][1024][128]
  u16* kbb     = qb + (size_t)32 * 1024 * 128;                // [8][4096][128]
  u16* vT      = kbb + (size_t)8 * 4096 * 128;                // [8][128][4096]
  u16* ctxb    = vT + (size_t)8 * 4096 * 128;                 // [1024][4096]
  // attn partials ALIAS Wt_proj (dead after gemm1; rewritten each call): 32.5MB < 48MB
  float* Opart = (float*)d_ws;                                // [2][1024][4096] f32
  float* Ml    = Opart + (size_t)2 * 1024 * 4096;             // [2][32][1024][2] f32

  float* outp   = (float*)d_out;
  float* keys   = outp + (size_t)4194304;
  float* values = outp + (size_t)8388608;

  wtrans<<<4096, 256, 0, stream>>>(Wq, Wt_proj, 4096, 64, 0);
  wtrans<<<1024, 256, 0, stream>>>(Wk, Wt_proj, 1024, 16, 4096);
  wtrans<<<1024, 256, 0, stream>>>(Wv, Wt_proj, 1024, 16, 5120);
  wtrans<<<4096, 256, 0, stream>>>(Wo, Wt_out, 4096, 64, 0);
  cvt_bf16<<<4096, 256, 0, stream>>>(x, xb, 1048576);

  gemm_bt<<<768, 256, 0, stream>>>(xb, Wt_proj, qkv, 6144, 4096, 96);

  rope_q<<<2048, 256, 0, stream>>>(qkv, cosb, sinb, qb);
  rope_k<<<512, 256, 0, stream>>>(qkv, cosb, sinb, keys, kbb);
  copy_vnew<<<1024, 256, 0, stream>>>(qkv, values);
  prev_copy<<<3072, 256, 0, stream>>>(prev_k, prev_v, keys, values, kbb);
  vtrans<<<1024, 256, 0, stream>>>(prev_v, qkv, vT);

  attn_fwd<<<2048, 64, 0, stream>>>(qb, kbb, vT, Opart, Ml);
  attn_combine<<<4096, 256, 0, stream>>>(Opart, Ml, ctxb);

  gemm_bt<<<512, 256, 0, stream>>>(ctxb, Wt_out, outp, 4096, 4096, 64);
}

// Round 13
// 379.237 us; speedup vs baseline: 1.1582x; 1.1582x over previous
//
#include <hip/hip_runtime.h>
#include <hip/hip_bf16.h>

typedef unsigned short u16;
typedef unsigned int u32;
typedef __attribute__((ext_vector_type(4))) float f32x4;
typedef __attribute__((ext_vector_type(16))) float f32x16;
typedef __attribute__((ext_vector_type(8))) __bf16 bf16x8;
typedef __attribute__((ext_vector_type(4))) u16 u16x4;
typedef __attribute__((ext_vector_type(8))) u16 u16x8;
typedef __attribute__((ext_vector_type(4))) u32 u32x4;

#define START_POS 3072
#define NKV 4096
#define HD_ 128
#define SEQ 1024
#define DIN_ 4096
#define DQKV 6144

__device__ __forceinline__ void gll16(const void* g, void* l) {
  __builtin_amdgcn_global_load_lds((const __attribute__((address_space(1))) u32*)g,
                                   (__attribute__((address_space(3))) u32*)l, 16, 0, 0);
}
__device__ __forceinline__ u16 f2bf(float f) {
  u32 u = __builtin_bit_cast(u32, f);
  return (u16)((u + 0x7fffu + ((u >> 16) & 1u)) >> 16);
}
__device__ __forceinline__ u32 pack2bf(float a, float b) {
  __hip_bfloat162 t = __float22bfloat162_rn(float2{a, b});  // low=a, high=b, RNE
  u32 u; __builtin_memcpy(&u, &t, 4);
  return u;
}
__device__ __forceinline__ f32x4 mfma16(bf16x8 a, bf16x8 b, f32x4 c) {
  return __builtin_amdgcn_mfma_f32_16x16x32_bf16(a, b, c, 0, 0, 0);
}
__device__ __forceinline__ f32x16 mfma32(bf16x8 a, bf16x8 b, f32x16 c) {
  return __builtin_amdgcn_mfma_f32_32x32x16_bf16(a, b, c, 0, 0, 0);
}

// ---- transpose+convert W f32 [K=4096][N] -> Wt bf16 [N][4096] ----
__global__ __launch_bounds__(256) void wtrans(const float* __restrict__ W,
    u16* __restrict__ Wt, int N, int ntn, int row_off)
{
  __shared__ float T[64][68];
  int bid = blockIdx.x;
  int nt = bid % ntn, kt = bid / ntn;
  int t = threadIdx.x;
  int kl = t >> 4, nl4 = (t & 15) << 2;
#pragma unroll
  for (int r = 0; r < 4; r++) {
    int row = r * 16 + kl;
    f32x4 v = *(const f32x4*)(W + (size_t)(kt * 64 + row) * N + nt * 64 + nl4);
    T[row][nl4] = v[0]; T[row][nl4 + 1] = v[1]; T[row][nl4 + 2] = v[2]; T[row][nl4 + 3] = v[3];
  }
  __syncthreads();
  int nl = t >> 2, k0 = (t & 3) << 4;
  u16x8 lo, hi;
#pragma unroll
  for (int j = 0; j < 8; j++) lo[j] = f2bf(T[k0 + j][nl]);
#pragma unroll
  for (int j = 0; j < 8; j++) hi[j] = f2bf(T[k0 + 8 + j][nl]);
  u16* dst = Wt + (size_t)(row_off + nt * 64 + nl) * 4096 + kt * 64 + k0;
  *(u16x8*)dst = lo;
  *(u16x8*)(dst + 8) = hi;
}

// ---- f32 -> bf16 convert ----
__global__ __launch_bounds__(256) void cvt_bf16(const float* __restrict__ src,
    u16* __restrict__ dst, int n4)
{
  int i = blockIdx.x * 256 + threadIdx.x;
  if (i >= n4) return;
  f32x4 v = *(const f32x4*)(src + (size_t)i * 4);
  u16x4 o;
#pragma unroll
  for (int j = 0; j < 4; j++) o[j] = f2bf(v[j]);
  *(u16x4*)(dst + (size_t)i * 4) = o;
}

// ---- bf16 GEMM v2: 128x64 tile, BK=32, double-buffered LDS, 2-phase prefetch ----
__global__ __launch_bounds__(256) void gemm_bt(
    const u16* __restrict__ A, const u16* __restrict__ Bt,
    float* __restrict__ C, int N, int K, int nbx)
{
  __shared__ u16 As[2 * 128 * 32];
  __shared__ u16 Bs[2 * 64 * 32];
  int nwg = (int)gridDim.x;
  int orig = blockIdx.x;
  int q8 = nwg >> 3, r8 = nwg & 7;
  int xcd = orig & 7, jj = orig >> 3;
  int wgid = (xcd < r8 ? xcd * (q8 + 1) : r8 * (q8 + 1) + (xcd - r8) * q8) + jj;
  int by = wgid / nbx, bx = wgid % nbx;
  int tid = threadIdx.x, lane = tid & 63, wid = tid >> 6;
  int wr = wid >> 1, wc = wid & 1;
  int c = lane & 15, hh = lane >> 4;
  int lrow = wid * 16 + (lane >> 2);       // 0..63
  int ksl = (lane & 3) << 3;
  const u16* aS0 = A + (size_t)(by * 128 + lrow) * K + ksl;
  const u16* bS0 = Bt + (size_t)(bx * 64 + lrow) * K + ksl;

#define GSTAGE(buf, kk) do { \
  gll16(aS0 + (kk), As + (buf) * 4096 + wid * 512); \
  gll16(aS0 + (size_t)64 * K + (kk), As + (buf) * 4096 + 2048 + wid * 512); \
  gll16(bS0 + (kk), Bs + (buf) * 2048 + wid * 512); \
} while (0)

  f32x4 acc[4][2] = {};
  int nk = K >> 5;
  int cur = 0;
  GSTAGE(0, 0);
  __syncthreads();                          // tile 0 resident
  for (int kt = 0; kt < nk; kt++) {
    if (kt + 1 < nk) GSTAGE(cur ^ 1, (kt + 1) * 32);  // prefetch next (hides under compute)
    const u16* Ab = As + cur * 4096;
    const u16* Bb = Bs + cur * 2048;
    bf16x8 af[4], bf[2];
#pragma unroll
    for (int i = 0; i < 4; i++)
      af[i] = *(const bf16x8*)(Ab + (wr * 64 + i * 16 + c) * 32 + hh * 8);
#pragma unroll
    for (int i = 0; i < 2; i++)
      bf[i] = *(const bf16x8*)(Bb + (wc * 32 + i * 16 + c) * 32 + hh * 8);
    __builtin_amdgcn_s_setprio(1);
#pragma unroll
    for (int mi = 0; mi < 4; mi++)
#pragma unroll
      for (int ni = 0; ni < 2; ni++)
        acc[mi][ni] = mfma16(af[mi], bf[ni], acc[mi][ni]);
    __builtin_amdgcn_s_setprio(0);
    __syncthreads();                        // prefetch landed + all waves done with cur
    cur ^= 1;
  }
#undef GSTAGE
  int row0 = by * 128 + wr * 64 + hh * 4;
  int col0 = bx * 64 + wc * 32 + c;
#pragma unroll
  for (int mi = 0; mi < 4; mi++)
#pragma unroll
    for (int ni = 0; ni < 2; ni++)
#pragma unroll
      for (int i = 0; i < 4; i++)
        C[(size_t)(row0 + mi * 16 + i) * N + col0 + ni * 16] = acc[mi][ni][i];
}

// ---- RoPE on q part of qkv -> qb bf16 [32][1024][128] ----
__global__ __launch_bounds__(256) void rope_q(const float* __restrict__ qkv,
    const float* __restrict__ cosb, const float* __restrict__ sinb, u16* __restrict__ qb)
{
  int tid = blockIdx.x * 256 + threadIdx.x;  // 524288
  int dq = tid & 15, h = (tid >> 4) & 31, s = tid >> 9;
  int d = dq << 2;
  const float* base = qkv + (size_t)s * DQKV + h * HD_ + d;
  f32x4 a = *(const f32x4*)base;
  f32x4 b2 = *(const f32x4*)(base + 64);
  f32x4 cc = *(const f32x4*)(cosb + (size_t)(START_POS + s) * HD_ + d);
  f32x4 sn = *(const f32x4*)(sinb + (size_t)(START_POS + s) * HD_ + d);
  u16x4 o1, o2;
#pragma unroll
  for (int i = 0; i < 4; i++) {
    o1[i] = f2bf(a[i] * cc[i] - b2[i] * sn[i]);
    o2[i] = f2bf(b2[i] * cc[i] + a[i] * sn[i]);
  }
  u16* dst = qb + ((size_t)h * SEQ + s) * HD_ + d;
  *(u16x4*)dst = o1;
  *(u16x4*)(dst + 64) = o2;
}

// ---- RoPE on k part -> keys f32 output (pos>=3072) + kb bf16 ----
__global__ __launch_bounds__(256) void rope_k(const float* __restrict__ qkv,
    const float* __restrict__ cosb, const float* __restrict__ sinb,
    float* __restrict__ keys, u16* __restrict__ kbb)
{
  int tid = blockIdx.x * 256 + threadIdx.x;  // 131072
  int dq = tid & 15, g = (tid >> 4) & 7, s = tid >> 7;
  int d = dq << 2;
  const float* base = qkv + (size_t)s * DQKV + DIN_ + g * HD_ + d;
  f32x4 a = *(const f32x4*)base;
  f32x4 b2 = *(const f32x4*)(base + 64);
  f32x4 cc = *(const f32x4*)(cosb + (size_t)(START_POS + s) * HD_ + d);
  f32x4 sn = *(const f32x4*)(sinb + (size_t)(START_POS + s) * HD_ + d);
  f32x4 o1, o2;
  u16x4 p1, p2;
#pragma unroll
  for (int i = 0; i < 4; i++) {
    o1[i] = a[i] * cc[i] - b2[i] * sn[i];
    o2[i] = b2[i] * cc[i] + a[i] * sn[i];
    p1[i] = f2bf(o1[i]);
    p2[i] = f2bf(o2[i]);
  }
  size_t off = ((size_t)g * NKV + START_POS + s) * HD_ + d;
  *(f32x4*)(keys + off) = o1;
  *(f32x4*)(keys + off + 64) = o2;
  *(u16x4*)(kbb + off) = p1;
  *(u16x4*)(kbb + off + 64) = p2;
}

// ---- copy v part -> values f32 output (pos>=3072) ----
__global__ __launch_bounds__(256) void copy_vnew(const float* __restrict__ qkv,
    float* __restrict__ values)
{
  int tid = blockIdx.x * 256 + threadIdx.x;  // 262144
  int dq = tid & 31, g = (tid >> 5) & 7, s = tid >> 8;
  int d = dq << 2;
  f32x4 v = *(const f32x4*)(qkv + (size_t)s * DQKV + DIN_ + 1024 + g * HD_ + d);
  *(f32x4*)(values + ((size_t)g * NKV + START_POS + s) * HD_ + d) = v;
}

// ---- copy prev_k/prev_v -> keys/values f32 outputs + kb bf16 ----
__global__ __launch_bounds__(256) void prev_copy(const float* __restrict__ pk,
    const float* __restrict__ pv, float* __restrict__ keys, float* __restrict__ values,
    u16* __restrict__ kbb)
{
  int idx = blockIdx.x * 256 + threadIdx.x;  // 786432 quads
  int d4 = idx & 31;
  int rest = idx >> 5;
  int p = rest % 3072, g = rest / 3072;
  f32x4 kq = *(const f32x4*)(pk + (size_t)idx * 4);
  f32x4 vq = *(const f32x4*)(pv + (size_t)idx * 4);
  size_t off = ((size_t)g * NKV + p) * HD_ + d4 * 4;
  *(f32x4*)(keys + off) = kq;
  *(f32x4*)(values + off) = vq;
  u16x4 kb4;
#pragma unroll
  for (int i = 0; i < 4; i++) kb4[i] = f2bf(kq[i]);
  *(u16x4*)(kbb + off) = kb4;
}

// ---- build vT bf16 [8][128][4096] from prev_v (pos<3072) / qkv v-cols ----
__global__ __launch_bounds__(256) void vtrans(const float* __restrict__ pv,
    const float* __restrict__ qkv, u16* __restrict__ vT)
{
  __shared__ float T[64][68];
  int bid = blockIdx.x;  // 1024 = g(8) * pt(64) * dt(2)
  int dt = bid & 1, pt = (bid >> 1) & 63, g = bid >> 7;
  int t = threadIdx.x;
  int pl = t >> 4, dl4 = (t & 15) << 2;
#pragma unroll
  for (int r = 0; r < 4; r++) {
    int row = r * 16 + pl;
    int pos = pt * 64 + row;
    f32x4 v;
    if (pos < START_POS)
      v = *(const f32x4*)(pv + ((size_t)g * START_POS + pos) * HD_ + dt * 64 + dl4);
    else
      v = *(const f32x4*)(qkv + (size_t)(pos - START_POS) * DQKV + 5120 + g * HD_ + dt * 64 + dl4);
    T[row][dl4] = v[0]; T[row][dl4 + 1] = v[1]; T[row][dl4 + 2] = v[2]; T[row][dl4 + 3] = v[3];
  }
  __syncthreads();
  int dl = t >> 2, p0 = (t & 3) << 4;
  u16x8 lo, hi;
#pragma unroll
  for (int j = 0; j < 8; j++) lo[j] = f2bf(T[p0 + j][dl]);
#pragma unroll
  for (int j = 0; j < 8; j++) hi[j] = f2bf(T[p0 + 8 + j][dl]);
  u16* dst = vT + ((size_t)g * HD_ + dt * 64 + dl) * NKV + pt * 64 + p0;
  *(u16x8*)dst = lo;
  *(u16x8*)(dst + 8) = hi;
}

// ---- flash attention v5d: v5c (r11, 157us verified) + QK^T 2-chain split + setprio ----
__global__ __launch_bounds__(128, 2) void attn_fwd(
    const u16* __restrict__ qb, const u16* __restrict__ kb,
    const u16* __restrict__ vT, float* __restrict__ Opart, float* __restrict__ Ml)
{
  __shared__ u16 Ks[2 * 32 * 128];   // [buf][kv 32][d 128], 16B-slot XOR swizzle
  __shared__ u16 Vs[2 * 128 * 32];   // [buf][d 128][kv 32], 16B-slot XOR swizzle
  const float C2 = 0.12751744f;      // log2(e)/sqrt(128)
  int bid = blockIdx.x;
  int g = bid & 7, j = bid >> 3;     // XCD x owns KV group g=x; j in [0,128)
  int sp = j >> 6, jj = j & 63;
  int h = g * 4 + (jj >> 4), qt = jj & 15;
  int tid = threadIdx.x, lane = tid & 63, w = tid >> 6;
  int c32 = lane & 31, h8 = lane >> 5;
  int qw0 = qt * 64 + w * 32;
  bf16x8 Qf[8];
#pragma unroll
  for (int dc = 0; dc < 8; dc++)
    Qf[dc] = *(const bf16x8*)(qb + ((size_t)(h * 1024 + qw0 + c32)) * 128 + dc * 16 + h8 * 8);
  f32x16 O0 = {}, O1 = {}, O2 = {}, O3 = {};
  float Mx = -1e30f, Ls = 0.f;
  // balanced split: sp0 = [0, 49+qt) (provably unmasked), sp1 = [49+qt, 98+2qt)
  int t0 = sp ? (49 + qt) : 0;
  int t1 = sp ? (98 + 2 * qt) : (49 + qt);

#define STAGE_KV(tt, bo) do { \
  _Pragma("unroll") \
  for (int r = 0; r < 4; r++) { \
    int s = w * 256 + r * 64 + lane; \
    int krow = s >> 4, sl = s & 15; \
    gll16(kb + ((size_t)(g * 4096 + (tt) * 32 + krow)) * 128 + (sl ^ (krow & 7)) * 8, \
          Ks + (bo) + (w * 256 + r * 64) * 8); \
    int d = s >> 2, sl2 = s & 3; \
    gll16(vT + ((size_t)(g * 128 + d)) * 4096 + (tt) * 32 + (sl2 ^ ((d >> 1) & 3)) * 8, \
          Vs + (bo) + (w * 256 + r * 64) * 8); \
  } \
} while (0)

  int cur = 0;
  STAGE_KV(t0, 0);
  __syncthreads();
  int vxr = (c32 >> 1) & 3;  // ((32*db + c32)>>1)&3 == (c32>>1)&3 for all db
  for (int t = t0; t < t1; t++) {
    if (t + 1 < t1) STAGE_KV(t + 1, (cur ^ 1) * 4096);
    const u16* Kb = Ks + cur * 4096;
    const u16* Vb = Vs + cur * 4096;
    // S^T = K Q^T : two independent accumulator chains (halves MFMA dep latency)
    f32x16 S0 = {}, Sb = {};
    __builtin_amdgcn_s_setprio(1);
#pragma unroll
    for (int dc = 0; dc < 8; dc += 2) {
      int sxA = (2 * dc + h8) ^ (c32 & 7);
      int sxB = (2 * dc + 2 + h8) ^ (c32 & 7);
      bf16x8 kA = *(const bf16x8*)(Kb + (size_t)c32 * 128 + sxA * 8);
      bf16x8 kB = *(const bf16x8*)(Kb + (size_t)c32 * 128 + sxB * 8);
      S0 = mfma32(kA, Qf[dc], S0);
      Sb = mfma32(kB, Qf[dc + 1], Sb);
    }
    __builtin_amdgcn_s_setprio(0);
#pragma unroll
    for (int r = 0; r < 16; r++) S0[r] += Sb[r];
    // causal mask (only sp=1 blocks near diagonal)
    if (t * 32 + 31 > START_POS + qw0) {
      int qa = START_POS + qw0 + c32;
#pragma unroll
      for (int r = 0; r < 16; r++) {
        int kvo = t * 32 + (r & 3) + 8 * (r >> 2) + 4 * h8;
        if (kvo > qa) S0[r] = -1e30f;
      }
    }
    // row max: 15-op tree + cross-half via shfl_xor(32)
    float tm[16];
#pragma unroll
    for (int r = 0; r < 16; r++) tm[r] = S0[r];
#pragma unroll
    for (int sft = 8; sft >= 1; sft >>= 1)
#pragma unroll
      for (int r = 0; r < sft; r++) tm[r] = fmaxf(tm[r], tm[r + sft]);
    float full = fmaxf(tm[0], __shfl_xor(tm[0], 32));
    // defer-max (T13)
    if (!__all(full <= Mx + 62.0f)) {
      float Mn = fmaxf(Mx, full);
      float al = exp2f((Mx - Mn) * C2);
      Mx = Mn;
      Ls *= al;
#pragma unroll
      for (int r = 0; r < 16; r++) { O0[r] *= al; O1[r] *= al; O2[r] *= al; O3[r] *= al; }
    }
#pragma unroll
    for (int r = 0; r < 16; r++) S0[r] = exp2f((S0[r] - Mx) * C2);
    // row sum
    float ts[16];
#pragma unroll
    for (int r = 0; r < 16; r++) ts[r] = S0[r];
#pragma unroll
    for (int sft = 8; sft >= 1; sft >>= 1)
#pragma unroll
      for (int r = 0; r < sft; r++) ts[r] = ts[r] + ts[r + sft];
    Ls += ts[0] + __shfl_xor(ts[0], 32);
    // pack P + cross-half exchange (verified v4 routing)
    u32 pk0[8], x0[8];
#pragma unroll
    for (int m = 0; m < 8; m++) pk0[m] = pack2bf(S0[2 * m], S0[2 * m + 1]);
#pragma unroll
    for (int m = 0; m < 8; m++) x0[m] = __shfl_xor(pk0[m], 32);
    bf16x8 pbf[2];
    {
      u32x4 f0 = { h8 ? x0[2] : pk0[0], h8 ? x0[3] : pk0[1],
                   h8 ? pk0[2] : x0[0], h8 ? pk0[3] : x0[1] };
      u32x4 f1 = { h8 ? x0[6] : pk0[4], h8 ? x0[7] : pk0[5],
                   h8 ? pk0[6] : x0[4], h8 ? pk0[7] : x0[5] };
      pbf[0] = __builtin_bit_cast(bf16x8, f0);
      pbf[1] = __builtin_bit_cast(bf16x8, f1);
    }
    // O^T += V^T P^T
    __builtin_amdgcn_s_setprio(1);
#pragma unroll
    for (int kc = 0; kc < 2; kc++) {
      int sv = 2 * kc + h8;
      int sx = (sv ^ vxr) * 8;
      {
        bf16x8 vf = *(const bf16x8*)(Vb + (size_t)(0 * 32 + c32) * 32 + sx);
        O0 = mfma32(vf, pbf[kc], O0);
      }
      {
        bf16x8 vf = *(const bf16x8*)(Vb + (size_t)(1 * 32 + c32) * 32 + sx);
        O1 = mfma32(vf, pbf[kc], O1);
      }
      {
        bf16x8 vf = *(const bf16x8*)(Vb + (size_t)(2 * 32 + c32) * 32 + sx);
        O2 = mfma32(vf, pbf[kc], O2);
      }
      {
        bf16x8 vf = *(const bf16x8*)(Vb + (size_t)(3 * 32 + c32) * 32 + sx);
        O3 = mfma32(vf, pbf[kc], O3);
      }
    }
    __builtin_amdgcn_s_setprio(0);
    __syncthreads();
    cur ^= 1;
  }
#undef STAGE_KV
  // epilogue: raw partial O (f32) + (Mx, Ls)
  {
    float* Orow = Opart + (size_t)sp * 4194304 + (size_t)(qw0 + c32) * 4096 + h * 128;
#pragma unroll
    for (int a = 0; a < 4; a++) {
      f32x4 o0, o1, o2, o3;
#pragma unroll
      for (int b = 0; b < 4; b++) {
        o0[b] = O0[4 * a + b]; o1[b] = O1[4 * a + b];
        o2[b] = O2[4 * a + b]; o3[b] = O3[4 * a + b];
      }
      int d0 = 8 * a + 4 * h8;
      *(f32x4*)(Orow + d0) = o0;
      *(f32x4*)(Orow + 32 + d0) = o1;
      *(f32x4*)(Orow + 64 + d0) = o2;
      *(f32x4*)(Orow + 96 + d0) = o3;
    }
    if (h8 == 0) {
      float* mp = Ml + ((size_t)(sp * 32 + h) * 1024 + qw0 + c32) * 2;
      mp[0] = Mx; mp[1] = Ls;
    }
  }
}

// ---- combine the two KV-split halves -> ctxb bf16 ----
__global__ __launch_bounds__(256) void attn_combine(const float* __restrict__ Opart,
    const float* __restrict__ Ml, u16* __restrict__ ctxb)
{
  int idx = blockIdx.x * 256 + threadIdx.x;  // 1048576
  int q = idx >> 10, c4 = idx & 1023;
  int col = c4 * 4, h = col >> 7;
  const float* m0p = Ml + ((size_t)h * 1024 + q) * 2;
  const float* m1p = Ml + ((size_t)(32 + h) * 1024 + q) * 2;
  float m0 = m0p[0], l0 = m0p[1];
  float m1 = m1p[0], l1 = m1p[1];
  float M = fmaxf(m0, m1);
  float w0 = exp2f((m0 - M) * 0.12751744f);
  float w1 = exp2f((m1 - M) * 0.12751744f);
  float inv = 1.0f / (l0 * w0 + l1 * w1);
  f32x4 a = *(const f32x4*)(Opart + (size_t)q * 4096 + col);
  f32x4 b = *(const f32x4*)(Opart + 4194304 + (size_t)q * 4096 + col);
  u16x4 o;
#pragma unroll
  for (int i = 0; i < 4; i++) o[i] = f2bf((a[i] * w0 + b[i] * w1) * inv);
  *(u16x4*)(ctxb + (size_t)q * 4096 + col) = o;
}

extern "C" void kernel_launch(void* const* d_in, const int* in_sizes, int n_in,
                              void* d_out, int out_size, void* d_ws, size_t ws_size,
                              hipStream_t stream) {
  const float* x      = (const float*)d_in[0];
  const float* cosb   = (const float*)d_in[2];
  const float* sinb   = (const float*)d_in[3];
  const float* prev_k = (const float*)d_in[5];
  const float* prev_v = (const float*)d_in[6];
  const float* Wq     = (const float*)d_in[7];
  const float* Wk     = (const float*)d_in[8];
  const float* Wv     = (const float*)d_in[9];
  const float* Wo     = (const float*)d_in[10];

  // workspace layout (~144 MB)
  u16* Wt_proj = (u16*)d_ws;                                  // [6144][4096] bf16 (48MB)
  u16* Wt_out  = Wt_proj + (size_t)6144 * 4096;               // [4096][4096] bf16
  u16* xb      = Wt_out + (size_t)4096 * 4096;                // [1024][4096] bf16
  float* qkv   = (float*)(xb + (size_t)1024 * 4096);          // [1024][6144] f32
  u16* qb      = (u16*)(qkv + (size_t)1024 * 6144);           // [32][1024][128]
  u16* kbb     = qb + (size_t)32 * 1024 * 128;                // [8][4096][128]
  u16* vT      = kbb + (size_t)8 * 4096 * 128;                // [8][128][4096]
  u16* ctxb    = vT + (size_t)8 * 4096 * 128;                 // [1024][4096]
  // attn partials ALIAS Wt_proj (dead after gemm1; rewritten each call): 32.5MB < 48MB
  float* Opart = (float*)d_ws;                                // [2][1024][4096] f32
  float* Ml    = Opart + (size_t)2 * 1024 * 4096;             // [2][32][1024][2] f32

  float* outp   = (float*)d_out;
  float* keys   = outp + (size_t)4194304;
  float* values = outp + (size_t)8388608;

  wtrans<<<4096, 256, 0, stream>>>(Wq, Wt_proj, 4096, 64, 0);
  wtrans<<<1024, 256, 0, stream>>>(Wk, Wt_proj, 1024, 16, 4096);
  wtrans<<<1024, 256, 0, stream>>>(Wv, Wt_proj, 1024, 16, 5120);
  wtrans<<<4096, 256, 0, stream>>>(Wo, Wt_out, 4096, 64, 0);
  cvt_bf16<<<4096, 256, 0, stream>>>(x, xb, 1048576);

  gemm_bt<<<768, 256, 0, stream>>>(xb, Wt_proj, qkv, 6144, 4096, 96);

  rope_q<<<2048, 256, 0, stream>>>(qkv, cosb, sinb, qb);
  rope_k<<<512, 256, 0, stream>>>(qkv, cosb, sinb, keys, kbb);
  copy_vnew<<<1024, 256, 0, stream>>>(qkv, values);
  prev_copy<<<3072, 256, 0, stream>>>(prev_k, prev_v, keys, values, kbb);
  vtrans<<<1024, 256, 0, stream>>>(prev_v, qkv, vT);

  attn_fwd<<<1024, 128, 0, stream>>>(qb, kbb, vT, Opart, Ml);
  attn_combine<<<4096, 256, 0, stream>>>(Opart, Ml, ctxb);

  gemm_bt<<<512, 256, 0, stream>>>(ctxb, Wt_out, outp, 4096, 4096, 64);
}